// Round 2
// baseline (515.363 us; speedup 1.0000x reference)
//
#include <hip/hip_runtime.h>

// delta_layer: B=32, T=4096, D=256, window=2 (fp32).
// out[b,t] = concat(x[b,t], delta[b,t], double_delta[b,t])  -> 3*D floats.
// delta[t]  = (x[c(t+1)]-x[c(t-1)])/2 + (x[c(t+2)]-x[c(t-2)])/4, c = clamp to [0,T-1]
// ddelta[t] = (delta[c(t+1)]-delta[c(t-1)])/2 + (delta[c(t+2)]-delta[c(t-2)])/4
//
// Stateless max-TLP design: one thread per (b, t, d4). 9 independent row loads
// (interior fast path, no clamp), deltas recomputed per-thread in the exact
// reference arithmetic order, 3 contiguous stores. L1/L2 absorb the 9x
// instruction-level reuse; chunked XCD swizzle gives each XCD 4 whole batches
// so no halo row is ever fetched by two XCDs. 131072 waves, no dep chains.
//
// NOTE: in_sizes[] is in ELEMENTS (fp32 count), not bytes — round-1 lesson.

#define TT   4096
#define D4   64    // float4 chunks per input row
#define O4   192   // float4 chunks per output row (3*256/4)

__device__ __forceinline__ float4 dcomb(const float4 p1, const float4 m1,
                                        const float4 p2, const float4 m2) {
    float4 r;
    r.x = (p1.x - m1.x) * 0.5f + (p2.x - m2.x) * 0.25f;
    r.y = (p1.y - m1.y) * 0.5f + (p2.y - m2.y) * 0.25f;
    r.z = (p1.z - m1.z) * 0.5f + (p2.z - m2.z) * 0.25f;
    r.w = (p1.w - m1.w) * 0.5f + (p2.w - m2.w) * 0.25f;
    return r;
}

__device__ __forceinline__ int clampT(int s) {
    return s < 0 ? 0 : (s > TT - 1 ? TT - 1 : s);
}

__global__ __launch_bounds__(256) void delta_layer_kernel(
        const float* __restrict__ x, float* __restrict__ out) {
    // Chunked bijective XCD swizzle (gridDim.x = 32768, divisible by 8):
    // XCD k gets a contiguous eighth of the work space = 4 complete batches,
    // so no halo row is fetched from HBM by two different XCDs.
    int bid = blockIdx.x;
    int swz = (gridDim.x & 7) == 0
                  ? (bid & 7) * (gridDim.x >> 3) + (bid >> 3)
                  : bid;

    int idx = swz * 256 + (int)threadIdx.x;
    int d4  = idx & (D4 - 1);
    int g   = idx >> 6;              // wave-uniform: global row index b*TT + t
    int t   = g & (TT - 1);
    int b   = g >> 12;               // TT = 2^12

    const float4* xr = reinterpret_cast<const float4*>(x)
                       + (size_t)g * D4 + d4;          // row t of batch b
    float4* ob = reinterpret_cast<float4*>(out)
                 + (size_t)g * O4 + d4;

    if (t >= 4 && t <= TT - 5) {
        // ---- interior fast path: 9 unclamped independent loads ----
        float4 xm4 = xr[-4 * D4];
        float4 xm3 = xr[-3 * D4];
        float4 xm2 = xr[-2 * D4];
        float4 xm1 = xr[-1 * D4];
        float4 x0  = xr[0];
        float4 xp1 = xr[1 * D4];
        float4 xp2 = xr[2 * D4];
        float4 xp3 = xr[3 * D4];
        float4 xp4 = xr[4 * D4];

        // deltas in exact reference order (same dcomb as verified kernel)
        float4 dm2 = dcomb(xm1, xm3, x0,  xm4);   // delta[t-2]
        float4 dm1 = dcomb(x0,  xm2, xp1, xm3);   // delta[t-1]
        float4 d0  = dcomb(xp1, xm1, xp2, xm2);   // delta[t]
        float4 dp1 = dcomb(xp2, x0,  xp3, xm1);   // delta[t+1]
        float4 dp2 = dcomb(xp3, xp1, xp4, x0);    // delta[t+2]

        ob[0]      = x0;
        ob[D4]     = d0;
        ob[2 * D4] = dcomb(dp1, dm1, dp2, dm2);   // ddelta[t]
    } else {
        // ---- boundary slow path (t in {0..3, TT-4..TT-1}; wave-uniform) ----
        const float4* xb = reinterpret_cast<const float4*>(x)
                           + (size_t)b * TT * D4 + d4;
        auto ldc = [&](int r) -> float4 { return xb[clampT(r) * D4]; };
        auto deltaAt = [&](int r) -> float4 {   // r must be a valid row
            return dcomb(ldc(r + 1), ldc(r - 1), ldc(r + 2), ldc(r - 2));
        };
        float4 dm2 = deltaAt(clampT(t - 2));
        float4 dm1 = deltaAt(clampT(t - 1));
        float4 d0  = deltaAt(t);
        float4 dp1 = deltaAt(clampT(t + 1));
        float4 dp2 = deltaAt(clampT(t + 2));

        ob[0]      = ldc(t);
        ob[D4]     = d0;
        ob[2 * D4] = dcomb(dp1, dm1, dp2, dm2);
    }
}

extern "C" void kernel_launch(void* const* d_in, const int* in_sizes, int n_in,
                              void* d_out, int out_size, void* d_ws, size_t ws_size,
                              hipStream_t stream) {
    const float* x = (const float*)d_in[0];
    float* out = (float*)d_out;
    // one thread per float4 of input: in_sizes[0] is ELEMENT count -> /4
    int nthreads = in_sizes[0] / 4;
    int blocks = (nthreads + 255) / 256;
    delta_layer_kernel<<<blocks, 256, 0, stream>>>(x, out);
}

// Round 4
// 499.438 us; speedup vs baseline: 1.0319x; 1.0319x over previous
//
#include <hip/hip_runtime.h>

// delta_layer: B=32, T=4096, D=256, window=2 (fp32).
// out[b,t] = concat(x[b,t], delta[b,t], double_delta[b,t])  -> 3*D floats.
// delta[t]  = (x[c(t+1)]-x[c(t-1)])/2 + (x[c(t+2)]-x[c(t-2)])/4, c = clamp to [0,T-1]
// ddelta[t] = (delta[c(t+1)]-delta[c(t-1)])/2 + (delta[c(t+2)]-delta[c(t-2)])/4
//
// Round-2 lesson: stateless per-t recompute ran AT the HBM roofline but with 9x
// read amplification (L2 thrashed by the 3x write stream) -> 1.6 GB traffic.
// This version: LDS t-tiling. Block = 256 threads = 32 rows x full D of one
// batch. Stage 40 rows (32 + 4 halo each side, 40 KB) to LDS ONCE -> sync ->
// each thread computes 8 outputs with the round-2-verified interior dcomb
// sequence, reading x from LDS. Read amplification = 40/32 = 1.25x GUARANTEED,
// independent of L2. Boundary chunks (first/last per batch) use the verified
// global clamped slow path wholesale (no double-clamp cases in the LDS path).
// Output stores are nontemporal (write-once stream, keep it out of L2).
//
// Round-3 lesson: __builtin_nontemporal_store needs a NATIVE clang vector,
// not HIP_vector_type float4 -> bit-cast through ext_vector_type(4) float.
// NOTE: in_sizes[] is in ELEMENTS (fp32 count), not bytes.

#define TT     4096
#define D4     64     // float4 chunks per input row
#define O4     192    // float4 chunks per output row (3*256/4)
#define TCH    32     // t-rows per block
#define NCH    (TT / TCH)        // 128 chunks per batch
#define SROWS  (TCH + 8)         // staged rows (4 halo each side) = 40

typedef float nfloat4 __attribute__((ext_vector_type(4)));

__device__ __forceinline__ void ntstore(const float4 v, float4* p) {
    union { float4 f; nfloat4 n; } u;
    u.f = v;
    __builtin_nontemporal_store(u.n, reinterpret_cast<nfloat4*>(p));
}

__device__ __forceinline__ float4 dcomb(const float4 p1, const float4 m1,
                                        const float4 p2, const float4 m2) {
    float4 r;
    r.x = (p1.x - m1.x) * 0.5f + (p2.x - m2.x) * 0.25f;
    r.y = (p1.y - m1.y) * 0.5f + (p2.y - m2.y) * 0.25f;
    r.z = (p1.z - m1.z) * 0.5f + (p2.z - m2.z) * 0.25f;
    r.w = (p1.w - m1.w) * 0.5f + (p2.w - m2.w) * 0.25f;
    return r;
}

__device__ __forceinline__ int clampT(int s) {
    return s < 0 ? 0 : (s > TT - 1 ? TT - 1 : s);
}

__global__ __launch_bounds__(256) void delta_layer_kernel(
        const float* __restrict__ x, float* __restrict__ out) {
    __shared__ float4 sh[SROWS * D4];   // 40 KB

    // Chunked bijective XCD swizzle (grid = 4096 blocks, divisible by 8):
    // XCD k gets a contiguous range of chunks = 4 whole batches -> halo rows
    // shared by neighbor blocks stay on one XCD's L2.
    int bid = blockIdx.x;
    int swz = (gridDim.x & 7) == 0
                  ? (bid & 7) * (gridDim.x >> 3) + (bid >> 3)
                  : bid;

    int ct = swz & (NCH - 1);        // t-chunk index 0..127
    int b  = swz >> 7;               // batch
    int r0 = ct * TCH;               // first output row of this block
    int tid = (int)threadIdx.x;

    const float4* x4 = reinterpret_cast<const float4*>(x);
    float4* out4 = reinterpret_cast<float4*>(out);

    if (ct >= 1 && ct <= NCH - 2) {
        // ================= interior: LDS-staged fast path =================
        // Stage rows r0-4 .. r0+35 (all valid, no clamping needed).
        const float4* src = x4 + ((size_t)(b * TT + r0 - 4)) * D4;
        #pragma unroll
        for (int i = 0; i < SROWS * D4 / 256; ++i) {   // 10 iterations
            int s = i * 256 + tid;
            sh[s] = src[s];
        }
        __syncthreads();

        #pragma unroll
        for (int j = 0; j < 8; ++j) {
            int o    = j * 256 + tid;
            int trow = o >> 6;           // 0..31, wave-uniform
            int d4   = o & 63;

            const float4* L = &sh[trow * D4 + d4];   // = row (r0+trow)-4
            float4 xm4 = L[0 * D4];
            float4 xm3 = L[1 * D4];
            float4 xm2 = L[2 * D4];
            float4 xm1 = L[3 * D4];
            float4 x0  = L[4 * D4];
            float4 xp1 = L[5 * D4];
            float4 xp2 = L[6 * D4];
            float4 xp3 = L[7 * D4];
            float4 xp4 = L[8 * D4];

            // exact round-2-verified interior sequence
            float4 dm2 = dcomb(xm1, xm3, x0,  xm4);   // delta[t-2]
            float4 dm1 = dcomb(x0,  xm2, xp1, xm3);   // delta[t-1]
            float4 d0  = dcomb(xp1, xm1, xp2, xm2);   // delta[t]
            float4 dp1 = dcomb(xp2, x0,  xp3, xm1);   // delta[t+1]
            float4 dp2 = dcomb(xp3, xp1, xp4, x0);    // delta[t+2]
            float4 dd  = dcomb(dp1, dm1, dp2, dm2);   // ddelta[t]

            float4* ob = out4 + ((size_t)(b * TT + r0 + trow)) * O4 + d4;
            ntstore(x0, &ob[0]);
            ntstore(d0, &ob[D4]);
            ntstore(dd, &ob[2 * D4]);
        }
    } else {
        // ============ boundary chunks: verified global slow path ============
        const float4* xb0 = x4 + (size_t)b * TT * D4;
        #pragma unroll
        for (int j = 0; j < 8; ++j) {
            int o    = j * 256 + tid;
            int trow = o >> 6;
            int d4   = o & 63;
            int t    = r0 + trow;

            const float4* xb = xb0 + d4;
            auto ldc = [&](int r) -> float4 { return xb[clampT(r) * D4]; };
            auto deltaAt = [&](int r) -> float4 {   // r must be a valid row
                return dcomb(ldc(r + 1), ldc(r - 1), ldc(r + 2), ldc(r - 2));
            };
            float4 dm2 = deltaAt(clampT(t - 2));
            float4 dm1 = deltaAt(clampT(t - 1));
            float4 d0  = deltaAt(t);
            float4 dp1 = deltaAt(clampT(t + 1));
            float4 dp2 = deltaAt(clampT(t + 2));
            float4 dd  = dcomb(dp1, dm1, dp2, dm2);

            float4* ob = out4 + ((size_t)(b * TT + t)) * O4 + d4;
            ntstore(ldc(t), &ob[0]);
            ntstore(d0,     &ob[D4]);
            ntstore(dd,     &ob[2 * D4]);
        }
    }
}

extern "C" void kernel_launch(void* const* d_in, const int* in_sizes, int n_in,
                              void* d_out, int out_size, void* d_ws, size_t ws_size,
                              hipStream_t stream) {
    const float* x = (const float*)d_in[0];
    float* out = (float*)d_out;
    // in_sizes[0] is ELEMENT count: rows = /256; blocks = rows / TCH
    int rows = in_sizes[0] / 256;
    int blocks = rows / TCH;            // 4096 for B=32
    delta_layer_kernel<<<blocks, 256, 0, stream>>>(x, out);
}

// Round 5
// 493.495 us; speedup vs baseline: 1.0443x; 1.0120x over previous
//
#include <hip/hip_runtime.h>

// delta_layer: B=32, T=4096, D=256, window=2 (fp32).
// out[b,t] = concat(x[b,t], delta[b,t], double_delta[b,t])  -> 3*D floats.
// delta[t]  = (x[c(t+1)]-x[c(t-1)])/2 + (x[c(t+2)]-x[c(t-2)])/4, c = clamp to [0,T-1]
// ddelta[t] = (delta[c(t+1)]-delta[c(t-1)])/2 + (delta[c(t+2)]-delta[c(t-2)])/4
//
// Round-4 post-mortem: LDS-tiled version was ON-CHIP-bound, not memory-bound:
// 6 dcombs/elem (delta recomputed 5x) = ~82 us aggregate VALU + ~46 us LDS pipe
// + 2-phase barriers at 4 blocks/CU  ->  244 us vs 91 us HBM floor.
// This version: register-ring, short run, NO LDS, NO barriers. Thread owns 8
// consecutive t at one d4: 16 hoisted independent row loads, 12 deltas computed
// ONCE into registers, 8 ddeltas, 24 nt-stores. 2.5 dcombs/elem (2.4x VALU cut).
// Read amplification capped by REGISTERS at 2.0x worst case (168-268 MB actual
// with L1/L2 wave-overlap dedupe) -- round-2's L2-thrash failure mode is
// structurally excluded. 16384 waves, zero sync.
//
// NOTE: in_sizes[] is in ELEMENTS (fp32 count), not bytes.

#define TT    4096
#define D4    64     // float4 chunks per input row
#define O4    192    // float4 chunks per output row (3*256/4)
#define WRUN  8      // consecutive t-rows per thread
#define SEGS  (TT / WRUN)   // 512 wave-segments per batch

typedef float nfloat4 __attribute__((ext_vector_type(4)));

__device__ __forceinline__ void ntstore(const float4 v, float4* p) {
    union { float4 f; nfloat4 n; } u;
    u.f = v;
    __builtin_nontemporal_store(u.n, reinterpret_cast<nfloat4*>(p));
}

__device__ __forceinline__ float4 dcomb(const float4 p1, const float4 m1,
                                        const float4 p2, const float4 m2) {
    float4 r;
    r.x = (p1.x - m1.x) * 0.5f + (p2.x - m2.x) * 0.25f;
    r.y = (p1.y - m1.y) * 0.5f + (p2.y - m2.y) * 0.25f;
    r.z = (p1.z - m1.z) * 0.5f + (p2.z - m2.z) * 0.25f;
    r.w = (p1.w - m1.w) * 0.5f + (p2.w - m2.w) * 0.25f;
    return r;
}

__device__ __forceinline__ int clampT(int s) {
    return s < 0 ? 0 : (s > TT - 1 ? TT - 1 : s);
}

__global__ __launch_bounds__(256) void delta_layer_kernel(
        const float* __restrict__ x, float* __restrict__ out) {
    // Chunked bijective XCD swizzle (grid = 4096, divisible by 8): each XCD
    // gets a contiguous run of segments = 4 whole batches -> halo rows shared
    // by t-adjacent waves/blocks stay within one XCD's L2.
    int bid = blockIdx.x;
    int swz = (gridDim.x & 7) == 0
                  ? (bid & 7) * (gridDim.x >> 3) + (bid >> 3)
                  : bid;

    int idx = swz * 256 + (int)threadIdx.x;
    int d4  = idx & 63;              // lane = feature chunk (coalesced)
    int seg = idx >> 6;              // wave-uniform
    int tb  = seg & (SEGS - 1);      // t-segment 0..511
    int b   = seg >> 9;              // batch
    int w0  = tb * WRUN;             // first output row of this thread

    const float4* x4 = reinterpret_cast<const float4*>(x);
    float4* out4 = reinterpret_cast<float4*>(out);

    const float4* xr = x4 + ((size_t)(b * TT + w0)) * D4 + d4;
    float4* ob = out4 + ((size_t)(b * TT + w0)) * O4 + d4;

    if (w0 >= 4 && w0 + 11 <= TT - 1) {
        // ---------- interior fast path: all indices unclamped ----------
        // xq[i] = x[row w0 + i - 4], i = 0..15  (16 independent loads)
        float4 xq[16];
        #pragma unroll
        for (int i = 0; i < 16; ++i) xq[i] = xr[(i - 4) * D4];

        // d[j] = delta[row w0 + j - 2], j = 0..11 -- each delta computed ONCE
        // delta[r] = dcomb(x[r+1], x[r-1], x[r+2], x[r-2])
        float4 d[12];
        #pragma unroll
        for (int j = 0; j < 12; ++j)
            d[j] = dcomb(xq[j + 3], xq[j + 1], xq[j + 4], xq[j]);

        #pragma unroll
        for (int m = 0; m < 8; ++m) {
            // ddelta[t] = dcomb(delta[t+1], delta[t-1], delta[t+2], delta[t-2])
            float4 dd = dcomb(d[m + 3], d[m + 1], d[m + 4], d[m]);
            ntstore(xq[m + 4], &ob[m * O4]);            // x[t]
            ntstore(d[m + 2],  &ob[m * O4 + D4]);       // delta[t]
            ntstore(dd,        &ob[m * O4 + 2 * D4]);   // ddelta[t]
        }
    } else {
        // ---------- boundary segments (tb==0 or tb==511): verified clamped path
        const float4* xb = x4 + (size_t)b * TT * D4 + d4;
        auto ldc = [&](int r) -> float4 { return xb[clampT(r) * D4]; };
        auto deltaAt = [&](int r) -> float4 {   // r must be a valid row
            return dcomb(ldc(r + 1), ldc(r - 1), ldc(r + 2), ldc(r - 2));
        };
        #pragma unroll
        for (int m = 0; m < 8; ++m) {
            int t = w0 + m;
            float4 dm2 = deltaAt(clampT(t - 2));
            float4 dm1 = deltaAt(clampT(t - 1));
            float4 d0  = deltaAt(t);
            float4 dp1 = deltaAt(clampT(t + 1));
            float4 dp2 = deltaAt(clampT(t + 2));
            float4 dd  = dcomb(dp1, dm1, dp2, dm2);

            ntstore(ldc(t), &ob[m * O4]);
            ntstore(d0,     &ob[m * O4 + D4]);
            ntstore(dd,     &ob[m * O4 + 2 * D4]);
        }
    }
}

extern "C" void kernel_launch(void* const* d_in, const int* in_sizes, int n_in,
                              void* d_out, int out_size, void* d_ws, size_t ws_size,
                              hipStream_t stream) {
    const float* x = (const float*)d_in[0];
    float* out = (float*)d_out;
    // in_sizes[0] is ELEMENT count. rows = /256; threads = rows/WRUN*64;
    // blocks = threads/256 = rows/32  (= 4096 for B=32, divisible by 8)
    int rows = in_sizes[0] / 256;
    int blocks = rows / 32;
    delta_layer_kernel<<<blocks, 256, 0, stream>>>(x, out);
}